// Round 3
// baseline (190.990 us; speedup 1.0000x reference)
//
#include <hip/hip_runtime.h>

#define NB   128   // images
#define NP   512   // pairs per image
#define NC   150   // foreground classes
#define ND   1024  // PATH_DIM
#define ROWS 64    // rows per block
#define CHUNKS (NP / ROWS)   // 8 chunks per image

typedef float  f4 __attribute__((ext_vector_type(4)));  // native vector: OK for nontemporal builtin
typedef float  f2 __attribute__((ext_vector_type(2)));
typedef int    i4 __attribute__((ext_vector_type(4)));

// Fused kernel. grid = NB*CHUNKS = 1024 blocks, block = 256 threads.
//   bid>>3 = image, bid&7 = 64-row chunk.
// Per block:
//   1. load preds[img] (512 ints as 128 int4), build multi-hot flags in LDS
//   2. each thread t computes y[4t..4t+3] = b[...] + sum_c flag[c]*W[d][c]
//      (4 rows x 150 FMA, float2 W loads -- W rows are 600B, 8B-aligned)
//   3. stream 64 rows of coalesced nontemporal float4 stores
__global__ __launch_bounds__(256) void labellayer_fused(const int* __restrict__ preds,
                                                        const float* __restrict__ W,
                                                        const float* __restrict__ bias,
                                                        float* __restrict__ out) {
    __shared__ float sflag[NC];
    const unsigned bid   = blockIdx.x;
    const unsigned img   = bid >> 3;
    const unsigned chunk = bid & 7;
    const unsigned t     = threadIdx.x;

    if (t < NC) sflag[t] = 0.0f;
    __syncthreads();

    // 512 preds = 128 int4 loads, threads 0..127
    if (t < NP / 4) {
        i4 c4 = ((const i4*)(preds + (size_t)img * NP))[t];
        sflag[c4.x - 1] = 1.0f;     // idempotent same-value races are benign
        sflag[c4.y - 1] = 1.0f;
        sflag[c4.z - 1] = 1.0f;
        sflag[c4.w - 1] = 1.0f;
    }
    __syncthreads();

    // compute this thread's float4 of y
    const f4 b4 = ((const f4*)bias)[t];
    float s0 = b4.x, s1 = b4.y, s2 = b4.z, s3 = b4.w;
    const f2* w0 = (const f2*)(W + (size_t)(4 * t + 0) * NC);
    const f2* w1 = (const f2*)(W + (size_t)(4 * t + 1) * NC);
    const f2* w2 = (const f2*)(W + (size_t)(4 * t + 2) * NC);
    const f2* w3 = (const f2*)(W + (size_t)(4 * t + 3) * NC);
    #pragma unroll 5
    for (int j = 0; j < NC / 2; ++j) {
        const float f0 = sflag[2 * j];       // wave-uniform LDS broadcast
        const float f1 = sflag[2 * j + 1];
        const f2 a0 = w0[j], a1 = w1[j], a2 = w2[j], a3 = w3[j];
        s0 += f0 * a0.x + f1 * a0.y;
        s1 += f0 * a1.x + f1 * a1.y;
        s2 += f0 * a2.x + f1 * a2.y;
        s3 += f0 * a3.x + f1 * a3.y;
    }
    f4 v;
    v.x = s0; v.y = s1; v.z = s2; v.w = s3;

    // stream stores: 64 rows x 256 float4/row, fully coalesced, nontemporal
    f4* obase = (f4*)out + ((size_t)img << 17);   // img * 512 rows * 256 f4
    const unsigned p0 = chunk * ROWS;
    #pragma unroll 4
    for (unsigned p = p0; p < p0 + ROWS; ++p) {
        __builtin_nontemporal_store(v, obase + ((size_t)p << 8) + t);
    }
}

extern "C" void kernel_launch(void* const* d_in, const int* in_sizes, int n_in,
                              void* d_out, int out_size, void* d_ws, size_t ws_size,
                              hipStream_t stream) {
    const int*   preds = (const int*)d_in[0];   // pair_preds [128,512] int32
    const float* W     = (const float*)d_in[1]; // [1024,150] fp32
    const float* bias  = (const float*)d_in[2]; // [1024] fp32
    float*       out   = (float*)d_out;         // [65536,1024] fp32

    labellayer_fused<<<dim3(NB * CHUNKS), dim3(256), 0, stream>>>(preds, W, bias, out);
}

// Round 4
// 190.847 us; speedup vs baseline: 1.0008x; 1.0008x over previous
//
#include <hip/hip_runtime.h>

#define NB   128   // images
#define NP   512   // pairs per image
#define NC   150   // foreground classes
#define ND   1024  // PATH_DIM
#define ROWS 64    // rows per block
#define CHUNKS (NP / ROWS)   // 8 chunks per image

typedef float  f4 __attribute__((ext_vector_type(4)));
typedef float  f2 __attribute__((ext_vector_type(2)));
typedef int    i4 __attribute__((ext_vector_type(4)));

// Fused kernel. grid = NB*CHUNKS = 1024 blocks, block = 256 threads.
//   bid>>3 = image, bid&7 = 64-row chunk.
// Per block:
//   1. load preds[img] (512 ints as 128 int4), build multi-hot flags in LDS
//   2. each thread t computes y[4t..4t+3] = b[...] + sum_c flag[c]*W[d][c]
//   3. stream 64 rows of coalesced float4 stores (PLAIN stores: retire into
//      L2 write-back fast; NT stores were latency-bound at 17% BW in R3)
__global__ __launch_bounds__(256) void labellayer_fused(const int* __restrict__ preds,
                                                        const float* __restrict__ W,
                                                        const float* __restrict__ bias,
                                                        float* __restrict__ out) {
    __shared__ float sflag[NC];
    const unsigned bid   = blockIdx.x;
    const unsigned img   = bid >> 3;
    const unsigned chunk = bid & 7;
    const unsigned t     = threadIdx.x;

    if (t < NC) sflag[t] = 0.0f;
    __syncthreads();

    // 512 preds = 128 int4 loads, threads 0..127
    if (t < NP / 4) {
        i4 c4 = ((const i4*)(preds + (size_t)img * NP))[t];
        sflag[c4.x - 1] = 1.0f;     // idempotent same-value races are benign
        sflag[c4.y - 1] = 1.0f;
        sflag[c4.z - 1] = 1.0f;
        sflag[c4.w - 1] = 1.0f;
    }
    __syncthreads();

    // compute this thread's float4 of y
    const f4 b4 = ((const f4*)bias)[t];
    float s0 = b4.x, s1 = b4.y, s2 = b4.z, s3 = b4.w;
    const f2* w0 = (const f2*)(W + (size_t)(4 * t + 0) * NC);
    const f2* w1 = (const f2*)(W + (size_t)(4 * t + 1) * NC);
    const f2* w2 = (const f2*)(W + (size_t)(4 * t + 2) * NC);
    const f2* w3 = (const f2*)(W + (size_t)(4 * t + 3) * NC);
    #pragma unroll 5
    for (int j = 0; j < NC / 2; ++j) {
        const float f0 = sflag[2 * j];       // wave-uniform LDS broadcast
        const float f1 = sflag[2 * j + 1];
        const f2 a0 = w0[j], a1 = w1[j], a2 = w2[j], a3 = w3[j];
        s0 += f0 * a0.x + f1 * a0.y;
        s1 += f0 * a1.x + f1 * a1.y;
        s2 += f0 * a2.x + f1 * a2.y;
        s3 += f0 * a3.x + f1 * a3.y;
    }
    f4 v;
    v.x = s0; v.y = s1; v.z = s2; v.w = s3;

    // stream stores: 64 rows x 256 float4/row, fully coalesced
    f4* obase = (f4*)out + ((size_t)img << 17);   // img * 512 rows * 256 f4
    const unsigned p0 = chunk * ROWS;
    #pragma unroll 4
    for (unsigned p = p0; p < p0 + ROWS; ++p) {
        obase[((size_t)p << 8) + t] = v;
    }
}

extern "C" void kernel_launch(void* const* d_in, const int* in_sizes, int n_in,
                              void* d_out, int out_size, void* d_ws, size_t ws_size,
                              hipStream_t stream) {
    const int*   preds = (const int*)d_in[0];   // pair_preds [128,512] int32
    const float* W     = (const float*)d_in[1]; // [1024,150] fp32
    const float* bias  = (const float*)d_in[2]; // [1024] fp32
    float*       out   = (float*)d_out;         // [65536,1024] fp32

    labellayer_fused<<<dim3(NB * CHUNKS), dim3(256), 0, stream>>>(preds, W, bias, out);
}

// Round 5
// 56.105 us; speedup vs baseline: 3.4042x; 3.4016x over previous
//
#include <hip/hip_runtime.h>

#define NB   128   // images
#define NP   512   // pairs per image
#define NC   150   // foreground classes
#define ND   1024  // PATH_DIM
#define BROWS 32   // rows per broadcast block
#define BCHUNKS (NP / BROWS)  // 16

typedef float  f4 __attribute__((ext_vector_type(4)));
typedef float  f2 __attribute__((ext_vector_type(2)));
typedef int    i4 __attribute__((ext_vector_type(4)));

// Kernel A: per image, build multi-hot in LDS, compute y[d] = b[d] + sum_c flag[c]*W[d][c],
// write into row 0 of the image's output block. ONE W row per thread (~10 cache
// lines per thread) -- keeps L1 transaction amplification bounded (the R3/R4
// fused kernel's 4-rows-per-thread over 1024 blocks was L1-transaction-bound).
// grid = 128*4: bid>>2 = image, bid&3 = 256-chunk of D.
__global__ __launch_bounds__(256) void compute_y_kernel(const int* __restrict__ preds,
                                                        const float* __restrict__ W,
                                                        const float* __restrict__ bias,
                                                        float* __restrict__ out) {
    __shared__ float sflag[NC];
    const unsigned bid  = blockIdx.x;
    const unsigned img  = bid >> 2;
    const unsigned dblk = bid & 3;
    const unsigned t    = threadIdx.x;

    if (t < NC) sflag[t] = 0.0f;
    __syncthreads();

    if (t < NP / 4) {
        i4 c4 = ((const i4*)(preds + (size_t)img * NP))[t];
        sflag[c4.x - 1] = 1.0f;     // idempotent; same-value races benign
        sflag[c4.y - 1] = 1.0f;
        sflag[c4.z - 1] = 1.0f;
        sflag[c4.w - 1] = 1.0f;
    }
    __syncthreads();

    const int d = (int)(dblk * 256 + t);
    const f2* w = (const f2*)(W + (size_t)d * NC);   // row is 600B, 8B-aligned
    float y = bias[d];
    #pragma unroll 5
    for (int j = 0; j < NC / 2; ++j) {
        const f2 a = w[j];
        y += sflag[2 * j] * a.x + sflag[2 * j + 1] * a.y;
    }
    out[(size_t)img * NP * ND + (size_t)d] = y;
}

// Kernel B: broadcast row 0 of each image to its remaining rows.
// grid = 128*16 = 2048 blocks (8/CU), block = 256. bid>>4 = image, bid&15 = 32-row chunk.
// Each thread: one f4 read of row 0 (L2-hot), then 32 coalesced f4 stores.
// Block writes a fully contiguous 128KB region.
__global__ __launch_bounds__(256) void broadcast_kernel(const f4* __restrict__ src,
                                                        f4* __restrict__ out) {
    const unsigned bid   = blockIdx.x;
    const unsigned img   = bid >> 4;
    const unsigned chunk = bid & 15;
    const unsigned t     = threadIdx.x;

    const size_t base = ((size_t)img << 17);        // img * 512 rows * 256 f4
    const f4 v = src[base + t];                     // row 0 (written by kernel A)

    unsigned p0 = chunk * BROWS;
    if (chunk == 0) p0 = 1;                         // don't rewrite row 0
    const unsigned p1 = chunk * BROWS + BROWS;

    #pragma unroll 4
    for (unsigned p = p0; p < p1; ++p) {
        out[base + ((size_t)p << 8) + t] = v;       // 256 f4 per row, coalesced
    }
}

extern "C" void kernel_launch(void* const* d_in, const int* in_sizes, int n_in,
                              void* d_out, int out_size, void* d_ws, size_t ws_size,
                              hipStream_t stream) {
    const int*   preds = (const int*)d_in[0];   // pair_preds [128,512] int32
    const float* W     = (const float*)d_in[1]; // [1024,150] fp32
    const float* bias  = (const float*)d_in[2]; // [1024] fp32
    float*       out   = (float*)d_out;         // [65536,1024] fp32

    compute_y_kernel<<<dim3(NB * 4), dim3(256), 0, stream>>>(preds, W, bias, out);
    broadcast_kernel<<<dim3(NB * BCHUNKS), dim3(256), 0, stream>>>((const f4*)out, (f4*)out);
}

// Round 6
// 55.888 us; speedup vs baseline: 3.4174x; 1.0039x over previous
//
#include <hip/hip_runtime.h>

#define NB   128   // images
#define NP   512   // pairs per image
#define NC   150   // foreground classes
#define ND   1024  // PATH_DIM
#define AD   64    // d-values per compute block
#define ADB  (ND / AD)        // 16 d-blocks per image
#define BROWS 32   // rows per broadcast block
#define BCHUNKS (NP / BROWS)  // 16

typedef float  f4 __attribute__((ext_vector_type(4)));
typedef int    i4 __attribute__((ext_vector_type(4)));

// Kernel A: grid = 128 img x 16 dblk = 2048 blocks, 256 threads.
// Block (img, dblk) computes y[d] for d in [dblk*64, dblk*64+64) and writes it
// into row 0 of the image's output block.
// W tile for a dblk is 64 rows x 150 = 37.5KB CONTIGUOUS -> cooperative f4
// load into LDS (coalesced, ~300 line transactions vs ~19200 for the old
// per-thread strided f2 reads -- that amplification was A's entire cost).
// Then 4 threads per d (one per wave) reduce a 150-class range from LDS.
__global__ __launch_bounds__(256) void compute_y_kernel(const int* __restrict__ preds,
                                                        const float* __restrict__ W,
                                                        const float* __restrict__ bias,
                                                        float* __restrict__ out) {
    __shared__ float wl[AD * NC];     // 38400 B, 16B-aligned tile copy
    __shared__ float sflag[NC];
    __shared__ float part[4][AD];

    const unsigned bid  = blockIdx.x;
    const unsigned img  = bid >> 4;
    const unsigned dblk = bid & 15;
    const unsigned t    = threadIdx.x;

    // issue preds load first so its latency overlaps the W coop-load
    i4 c4;
    if (t < NP / 4) c4 = ((const i4*)(preds + (size_t)img * NP))[t];

    if (t < NC) sflag[t] = 0.0f;

    // cooperative W tile load: 2400 f4 (dblk*38400 B offset, 16B-aligned)
    const f4* wsrc = (const f4*)(W + (size_t)dblk * AD * NC);
    f4* wdst = (f4*)wl;
    #pragma unroll
    for (int i = 0; i < 10; ++i) {
        unsigned g = i * 256u + t;
        if (g < (AD * NC) / 4) wdst[g] = wsrc[g];
    }
    __syncthreads();   // flag zeros visible

    if (t < NP / 4) {
        sflag[c4.x - 1] = 1.0f;   // idempotent; same-value races benign
        sflag[c4.y - 1] = 1.0f;
        sflag[c4.z - 1] = 1.0f;
        sflag[c4.w - 1] = 1.0f;
    }
    __syncthreads();   // flags + W tile visible

    // 4-way class split: wave q handles c in [q*38, min(q*38+38,150))
    const unsigned d = t & 63;
    const unsigned q = t >> 6;
    const unsigned c0 = q * 38;
    const unsigned c1 = (q == 3) ? NC : c0 + 38;
    float acc = 0.0f;
    const float* wrow = wl + (size_t)d * NC;
    for (unsigned c = c0; c < c1; ++c) {
        acc += sflag[c] * wrow[c];
    }
    part[q][d] = acc;
    __syncthreads();

    if (t < AD) {
        const unsigned dg = dblk * AD + t;
        float y = bias[dg] + part[0][t] + part[1][t] + part[2][t] + part[3][t];
        out[(size_t)img * NP * ND + dg] = y;   // row 0, 256B contiguous per block
    }
}

// Kernel B: broadcast row 0 of each image to its remaining rows. (Unchanged
// from R5 -- proven ~6.7+ TB/s.) grid = 128*16 = 2048 blocks (8/CU), 256 thr.
__global__ __launch_bounds__(256) void broadcast_kernel(const f4* __restrict__ src,
                                                        f4* __restrict__ out) {
    const unsigned bid   = blockIdx.x;
    const unsigned img   = bid >> 4;
    const unsigned chunk = bid & 15;
    const unsigned t     = threadIdx.x;

    const size_t base = ((size_t)img << 17);        // img * 512 rows * 256 f4
    const f4 v = src[base + t];                     // row 0 (written by kernel A)

    unsigned p0 = chunk * BROWS;
    if (chunk == 0) p0 = 1;                         // don't rewrite row 0
    const unsigned p1 = chunk * BROWS + BROWS;

    #pragma unroll 4
    for (unsigned p = p0; p < p1; ++p) {
        out[base + ((size_t)p << 8) + t] = v;       // 256 f4 per row, coalesced
    }
}

extern "C" void kernel_launch(void* const* d_in, const int* in_sizes, int n_in,
                              void* d_out, int out_size, void* d_ws, size_t ws_size,
                              hipStream_t stream) {
    const int*   preds = (const int*)d_in[0];   // pair_preds [128,512] int32
    const float* W     = (const float*)d_in[1]; // [1024,150] fp32
    const float* bias  = (const float*)d_in[2]; // [1024] fp32
    float*       out   = (float*)d_out;         // [65536,1024] fp32

    compute_y_kernel<<<dim3(NB * ADB), dim3(256), 0, stream>>>(preds, W, bias, out);
    broadcast_kernel<<<dim3(NB * BCHUNKS), dim3(256), 0, stream>>>((const f4*)out, (f4*)out);
}